// Round 6
// baseline (126.057 us; speedup 1.0000x reference)
//
#include <hip/hip_runtime.h>

// Problem constants
constexpr int N = 8192;
constexpr int C = 2048;
constexpr int ND = N + 4;                        // 8196
constexpr unsigned ADJ_CHUNKS = ND / 4;          // 2049 float4 per adj row
constexpr unsigned TOTAL4 = (unsigned)ND * ADJ_CHUNKS;   // 16,793,604
constexpr size_t XNEW_ELEMS = (size_t)ND * C;    // 16785408
constexpr int ATT_BLOCKS = 512;                  // 16 rows each
constexpr int ADJ_BLOCKS = 2048;                 // grid-stride, ~32 iters

#define C_DIAG 0.5f
#define C_LINK 0.015609764f                      /* 1/sqrt(2*2052) */
#define C_BLK  (1.0f / 2052.0f)

// True vector type (VGPR-resident, supports .x/.y/.z/.w swizzles).
typedef float f32x4 __attribute__((ext_vector_type(4)));

// ---------------------------------------------------------------------------
// adj streaming body: one PLAIN f32x4 store per 16B (R6: nt removed — R5's
// nontemporal stores were the suspected BW killer vs the 7 TB/s fill path).
// Values built with per-component ternaries -> v_cndmask, no scratch (R3 bug).
__device__ __forceinline__ void adj_body(float* __restrict__ adj,
                                         unsigned first, unsigned stride) {
    f32x4* __restrict__ out = reinterpret_cast<f32x4*>(adj);
    for (unsigned i4 = first; i4 < TOTAL4; i4 += stride) {
        const unsigned row   = i4 / ADJ_CHUNKS;          // magic-mul div
        const unsigned chunk = i4 - row * ADJ_CHUNKS;
        f32x4 v;
        if (row < (unsigned)N) {
            const bool dg = (chunk == (row >> 2));       // diagonal chunk
            const bool lk = (chunk == 2048u);            // row -> center chunk
            const unsigned r3 = row & 3u, sg = row >> 11;
            v.x = (dg && r3 == 0u) ? C_DIAG : ((lk && sg == 0u) ? C_LINK : 0.0f);
            v.y = (dg && r3 == 1u) ? C_DIAG : ((lk && sg == 1u) ? C_LINK : 0.0f);
            v.z = (dg && r3 == 2u) ? C_DIAG : ((lk && sg == 2u) ? C_LINK : 0.0f);
            v.w = (dg && r3 == 3u) ? C_DIAG : ((lk && sg == 3u) ? C_LINK : 0.0f);
        } else {
            const unsigned a = row - N;                  // center row 0..3
            const float f = (chunk == 2048u) ? C_BLK
                          : (((chunk >> 9) == a) ? C_LINK : 0.0f);
            v.x = f; v.y = f; v.z = f; v.w = f;
        }
        out[i4] = v;
    }
}

// ---------------------------------------------------------------------------
// Fused kernel: blocks [0, ATT_BLOCKS) do the attention pass (16 rows each,
// per-wave partials -> ws, no LDS, no syncthreads); remaining blocks stream
// the adj pattern. Both are HBM-bound; co-residency keeps BW saturated.
__global__ __launch_bounds__(256) void k_fused(const float* __restrict__ x,
                                               const float* __restrict__ attw,
                                               const float* __restrict__ attb,
                                               float* __restrict__ xnew,
                                               float* __restrict__ adj,
                                               float* __restrict__ part,
                                               float* __restrict__ wpart) {
    const int tid = threadIdx.x;
    if (blockIdx.x < ATT_BLOCKS) {
        const int wave = tid >> 6;
        const int lane = tid & 63;
        const int row0 = blockIdx.x * 16;
        const float bias = attb[0];

        f32x4 wv[8];
#pragma unroll
        for (int q = 0; q < 8; ++q)
            wv[q] = reinterpret_cast<const f32x4*>(attw)[lane + 64 * q];

        float acc[32];
#pragma unroll
        for (int k = 0; k < 32; ++k) acc[k] = 0.0f;
        float wacc = 0.0f;

        for (int r = 0; r < 4; ++r) {
            const int row = row0 + wave * 4 + r;
            const f32x4* xrow = reinterpret_cast<const f32x4*>(x + (size_t)row * C);
            f32x4* orow = reinterpret_cast<f32x4*>(xnew + (size_t)row * C);

            f32x4 xv[8];
            float dot = 0.0f;
#pragma unroll
            for (int q = 0; q < 8; ++q) {
                xv[q] = xrow[lane + 64 * q];
                dot += xv[q].x * wv[q].x + xv[q].y * wv[q].y +
                       xv[q].z * wv[q].z + xv[q].w * wv[q].w;
            }
#pragma unroll
            for (int off = 32; off > 0; off >>= 1) dot += __shfl_xor(dot, off, 64);
            const float wrow = dot + bias;
            wacc += wrow;
#pragma unroll
            for (int q = 0; q < 8; ++q) {
                acc[4 * q + 0] += wrow * xv[q].x;
                acc[4 * q + 1] += wrow * xv[q].y;
                acc[4 * q + 2] += wrow * xv[q].z;
                acc[4 * q + 3] += wrow * xv[q].w;
                orow[lane + 64 * q] = xv[q];             // x_new head copy
            }
        }

        // per-wave partial row (k_centers re-reads these)
        const int gw = blockIdx.x * 4 + wave;            // 0..2047
        f32x4* prow = reinterpret_cast<f32x4*>(part + (size_t)gw * C);
#pragma unroll
        for (int q = 0; q < 8; ++q) {
            f32x4 s;
            s.x = acc[4 * q];     s.y = acc[4 * q + 1];
            s.z = acc[4 * q + 2]; s.w = acc[4 * q + 3];
            prow[lane + 64 * q] = s;
        }
        if (lane == 0) wpart[gw] = wacc;                 // wacc is wave-uniform
    } else {
        adj_body(adj, (blockIdx.x - ATT_BLOCKS) * 256u + (unsigned)tid,
                 ADJ_BLOCKS * 256u);
    }
}

// ---------------------------------------------------------------------------
// centers[seg][c] = sum_k part[seg*512+k][c] / sum_k wpart[seg*512+k]
__global__ __launch_bounds__(256) void k_centers(const float* __restrict__ part,
                                                 const float* __restrict__ wpart,
                                                 float* __restrict__ xnew) {
    const int idx = blockIdx.x * 256 + threadIdx.x;      // 0..8191
    const int seg = idx >> 11;
    const int c   = idx & 2047;
    float wsum = 0.0f;
#pragma unroll 8
    for (int k = 0; k < 512; ++k) wsum += wpart[seg * 512 + k];
    float s = 0.0f;
#pragma unroll 8
    for (int k = 0; k < 512; ++k) s += part[(size_t)(seg * 512 + k) * C + c];
    xnew[(size_t)(N + seg) * C + c] = s / wsum;
}

// ---------------------------------------------------------------------------
// Fallback path (ws too small): atomic accumulation, standalone adj kernel.
__global__ __launch_bounds__(256) void k_adj_only(float* __restrict__ adj) {
    adj_body(adj, blockIdx.x * 256u + (unsigned)threadIdx.x, ADJ_BLOCKS * 256u);
}
__global__ __launch_bounds__(256) void k_zero(float* __restrict__ xnew,
                                              float* __restrict__ wseg) {
    int idx = blockIdx.x * 256 + threadIdx.x;
    if (idx < 4 * C) xnew[(size_t)N * C + idx] = 0.0f;
    if (idx < 4) wseg[idx] = 0.0f;
}
__global__ __launch_bounds__(256) void k_att_atomic(const float* __restrict__ x,
                                                    const float* __restrict__ attw,
                                                    const float* __restrict__ attb,
                                                    float* __restrict__ xnew,
                                                    float* __restrict__ wseg) {
    __shared__ float lnum[4][C];
    __shared__ float lw[4];
    const int tid = threadIdx.x, wave = tid >> 6, lane = tid & 63;
    const int row0 = blockIdx.x * 16, seg = blockIdx.x >> 7;
    const float bias = attb[0];
    f32x4 wv[8];
#pragma unroll
    for (int q = 0; q < 8; ++q)
        wv[q] = reinterpret_cast<const f32x4*>(attw)[lane + 64 * q];
    float acc[32];
#pragma unroll
    for (int k = 0; k < 32; ++k) acc[k] = 0.0f;
    float wacc = 0.0f;
    for (int r = 0; r < 4; ++r) {
        const int row = row0 + wave * 4 + r;
        const f32x4* xrow = reinterpret_cast<const f32x4*>(x + (size_t)row * C);
        f32x4* orow = reinterpret_cast<f32x4*>(xnew + (size_t)row * C);
        f32x4 xv[8];
        float dot = 0.0f;
#pragma unroll
        for (int q = 0; q < 8; ++q) {
            xv[q] = xrow[lane + 64 * q];
            dot += xv[q].x * wv[q].x + xv[q].y * wv[q].y +
                   xv[q].z * wv[q].z + xv[q].w * wv[q].w;
        }
#pragma unroll
        for (int off = 32; off > 0; off >>= 1) dot += __shfl_xor(dot, off, 64);
        const float wrow = dot + bias;
        wacc += wrow;
#pragma unroll
        for (int q = 0; q < 8; ++q) {
            acc[4 * q + 0] += wrow * xv[q].x;
            acc[4 * q + 1] += wrow * xv[q].y;
            acc[4 * q + 2] += wrow * xv[q].z;
            acc[4 * q + 3] += wrow * xv[q].w;
            orow[lane + 64 * q] = xv[q];
        }
    }
#pragma unroll
    for (int q = 0; q < 8; ++q) {
        f32x4 s;
        s.x = acc[4 * q];     s.y = acc[4 * q + 1];
        s.z = acc[4 * q + 2]; s.w = acc[4 * q + 3];
        reinterpret_cast<f32x4*>(&lnum[wave][0])[lane + 64 * q] = s;
    }
    if (lane == 0) lw[wave] = wacc;
    __syncthreads();
    for (int c = tid; c < C; c += 256) {
        float s = lnum[0][c] + lnum[1][c] + lnum[2][c] + lnum[3][c];
        atomicAdd(&xnew[(size_t)(N + seg) * C + c], s);
    }
    if (tid == 0) atomicAdd(&wseg[seg], lw[0] + lw[1] + lw[2] + lw[3]);
}
__global__ __launch_bounds__(256) void k_div(float* __restrict__ xnew,
                                             const float* __restrict__ wseg) {
    int idx = blockIdx.x * 256 + threadIdx.x;
    if (idx < 4 * C) xnew[(size_t)N * C + idx] /= wseg[idx >> 11];
}

// ---------------------------------------------------------------------------
extern "C" void kernel_launch(void* const* d_in, const int* in_sizes, int n_in,
                              void* d_out, int out_size, void* d_ws, size_t ws_size,
                              hipStream_t stream) {
    const float* x    = (const float*)d_in[0];
    const float* attw = (const float*)d_in[1];
    const float* attb = (const float*)d_in[2];
    float* xnew = (float*)d_out;                   // [8196, 2048]
    float* adj  = (float*)d_out + XNEW_ELEMS;      // [8196, 8196]

    const size_t ws_need = (2048 + (size_t)2048 * C) * sizeof(float);  // ~16.8 MB
    if (ws_size >= ws_need) {
        float* wpart = (float*)d_ws;               // [2048]
        float* part  = (float*)d_ws + 2048;        // [2048][C]
        k_fused<<<ATT_BLOCKS + ADJ_BLOCKS, 256, 0, stream>>>(
            x, attw, attb, xnew, adj, part, wpart);
        k_centers<<<32, 256, 0, stream>>>(part, wpart, xnew);
    } else {                                        // atomic fallback
        float* wseg = (float*)d_ws;                // [4]
        k_zero<<<32, 256, 0, stream>>>(xnew, wseg);
        k_att_atomic<<<N / 16, 256, 0, stream>>>(x, attw, attb, xnew, wseg);
        k_div<<<32, 256, 0, stream>>>(xnew, wseg);
        k_adj_only<<<ADJ_BLOCKS, 256, 0, stream>>>(adj);
    }
}

// Round 7
// 118.241 us; speedup vs baseline: 1.0661x; 1.0661x over previous
//
#include <hip/hip_runtime.h>

// Problem constants
constexpr int N = 8192;
constexpr int C = 2048;
constexpr int ND = N + 4;                        // 8196
constexpr size_t XNEW_ELEMS = (size_t)ND * C;    // 16785408
constexpr size_t ADJ_ELEMS  = (size_t)ND * ND;   // 67174416
constexpr int ATT_BLOCKS = 1024;                 // 8 rows per block, 2 per wave
constexpr int PARTS = ATT_BLOCKS;                // one partial row per block

#define C_DIAG 0.5f
#define C_LINK 0.015609764f                      /* 1/sqrt(2*2052) */
#define C_BLK  (1.0f / 2052.0f)

typedef float f32x4 __attribute__((ext_vector_type(4)));

// ---------------------------------------------------------------------------
// Attention pass: 1024 blocks x 8 rows (2 rows per wave, sequential), LDS
// block-combine -> part[block][C] (+ wpart[block]). Also copies x -> x_new.
__global__ __launch_bounds__(256) void k_att(const float* __restrict__ x,
                                             const float* __restrict__ attw,
                                             const float* __restrict__ attb,
                                             float* __restrict__ xnew,
                                             float* __restrict__ part,
                                             float* __restrict__ wpart) {
    __shared__ float lnum[4][C];                 // 32 KiB per-wave partials
    __shared__ float lw[4];

    const int tid  = threadIdx.x;
    const int wave = tid >> 6;
    const int lane = tid & 63;
    const int row0 = blockIdx.x * 8;
    const float bias = attb[0];

    f32x4 wv[8];
#pragma unroll
    for (int q = 0; q < 8; ++q)
        wv[q] = reinterpret_cast<const f32x4*>(attw)[lane + 64 * q];

    float acc[32];
#pragma unroll
    for (int k = 0; k < 32; ++k) acc[k] = 0.0f;
    float wacc = 0.0f;

    for (int r = 0; r < 2; ++r) {
        const int row = row0 + wave * 2 + r;
        const f32x4* xrow = reinterpret_cast<const f32x4*>(x + (size_t)row * C);
        f32x4* orow = reinterpret_cast<f32x4*>(xnew + (size_t)row * C);

        f32x4 xv[8];
        float dot = 0.0f;
#pragma unroll
        for (int q = 0; q < 8; ++q) {
            xv[q] = xrow[lane + 64 * q];
            dot += xv[q].x * wv[q].x + xv[q].y * wv[q].y +
                   xv[q].z * wv[q].z + xv[q].w * wv[q].w;
        }
#pragma unroll
        for (int off = 32; off > 0; off >>= 1) dot += __shfl_xor(dot, off, 64);
        const float wrow = dot + bias;
        wacc += wrow;
#pragma unroll
        for (int q = 0; q < 8; ++q) {
            acc[4 * q + 0] += wrow * xv[q].x;
            acc[4 * q + 1] += wrow * xv[q].y;
            acc[4 * q + 2] += wrow * xv[q].z;
            acc[4 * q + 3] += wrow * xv[q].w;
            orow[lane + 64 * q] = xv[q];         // x_new head copy
        }
    }

#pragma unroll
    for (int q = 0; q < 8; ++q) {
        f32x4 s;
        s.x = acc[4 * q];     s.y = acc[4 * q + 1];
        s.z = acc[4 * q + 2]; s.w = acc[4 * q + 3];
        reinterpret_cast<f32x4*>(&lnum[wave][0])[lane + 64 * q] = s;
    }
    if (lane == 0) lw[wave] = wacc;              // wacc is wave-uniform
    __syncthreads();

    const f32x4* l0 = reinterpret_cast<const f32x4*>(&lnum[0][0]);
    const f32x4* l1 = reinterpret_cast<const f32x4*>(&lnum[1][0]);
    const f32x4* l2 = reinterpret_cast<const f32x4*>(&lnum[2][0]);
    const f32x4* l3 = reinterpret_cast<const f32x4*>(&lnum[3][0]);
    f32x4* prow = reinterpret_cast<f32x4*>(part + (size_t)blockIdx.x * C);
#pragma unroll
    for (int c4 = tid; c4 < C / 4; c4 += 256)
        prow[c4] = l0[c4] + l1[c4] + l2[c4] + l3[c4];
    if (tid == 0) wpart[blockIdx.x] = lw[0] + lw[1] + lw[2] + lw[3];
}

// ---------------------------------------------------------------------------
// Fused finish: blocks 0-7 compute centers (f32x4 granularity, 1KB/wave/inst),
// blocks 8+ scatter the adj nonzeros (adj was bulk-zeroed by memset).
__global__ __launch_bounds__(256) void k_centers_nz(const float* __restrict__ part,
                                                    const float* __restrict__ wpart,
                                                    float* __restrict__ xnew,
                                                    float* __restrict__ adj) {
    const int tid = threadIdx.x;
    if (blockIdx.x < 8) {
        // 2048 threads: (seg, c4) with c4 in [0, 512)
        const int idx = blockIdx.x * 256 + tid;          // 0..2047
        const int seg = idx >> 9;
        const int c4  = idx & 511;
        const int kb  = PARTS / 4;                       // 256 partials per segment
        float wsum = 0.0f;
#pragma unroll 4
        for (int k = 0; k < kb; ++k) wsum += wpart[seg * kb + k];
        f32x4 s; s.x = 0.f; s.y = 0.f; s.z = 0.f; s.w = 0.f;
        const f32x4* p = reinterpret_cast<const f32x4*>(part) + (size_t)seg * kb * (C / 4) + c4;
#pragma unroll 4
        for (int k = 0; k < kb; ++k) s += p[(size_t)k * (C / 4)];
        const float inv = 1.0f / wsum;
        s.x *= inv; s.y *= inv; s.z *= inv; s.w *= inv;
        reinterpret_cast<f32x4*>(xnew + (size_t)(N + seg) * C)[c4] = s;
    } else {
        const int t = (blockIdx.x - 8) * 256 + tid;
        if (t < N) {
            adj[(size_t)t * ND + t] = C_DIAG;            // diagonal
            adj[(size_t)t * ND + N + (t >> 11)] = C_LINK; // row -> its center
        } else if (t < N + 4 * 2052) {
            const int u = t - N;
            const int i = u / 2052;                      // center index 0..3
            const int j = u - i * 2052;
            const size_t rowb = (size_t)(N + i) * ND;
            if (j < 2048) adj[rowb + i * 2048 + j] = C_LINK;  // center -> segment
            else          adj[rowb + N + (j - 2048)] = C_BLK; // 4x4 center block
        }
    }
}

// ---------------------------------------------------------------------------
// Fallback path (ws too small): atomic accumulation into d_out.
__global__ __launch_bounds__(256) void k_zero(float* __restrict__ xnew,
                                              float* __restrict__ wseg) {
    int idx = blockIdx.x * 256 + threadIdx.x;
    if (idx < 4 * C) xnew[(size_t)N * C + idx] = 0.0f;
    if (idx < 4) wseg[idx] = 0.0f;
}
__global__ __launch_bounds__(256) void k_att_atomic(const float* __restrict__ x,
                                                    const float* __restrict__ attw,
                                                    const float* __restrict__ attb,
                                                    float* __restrict__ xnew,
                                                    float* __restrict__ wseg) {
    __shared__ float lnum[4][C];
    __shared__ float lw[4];
    const int tid = threadIdx.x, wave = tid >> 6, lane = tid & 63;
    const int row0 = blockIdx.x * 8, seg = blockIdx.x >> 8;
    const float bias = attb[0];
    f32x4 wv[8];
#pragma unroll
    for (int q = 0; q < 8; ++q)
        wv[q] = reinterpret_cast<const f32x4*>(attw)[lane + 64 * q];
    float acc[32];
#pragma unroll
    for (int k = 0; k < 32; ++k) acc[k] = 0.0f;
    float wacc = 0.0f;
    for (int r = 0; r < 2; ++r) {
        const int row = row0 + wave * 2 + r;
        const f32x4* xrow = reinterpret_cast<const f32x4*>(x + (size_t)row * C);
        f32x4* orow = reinterpret_cast<f32x4*>(xnew + (size_t)row * C);
        f32x4 xv[8];
        float dot = 0.0f;
#pragma unroll
        for (int q = 0; q < 8; ++q) {
            xv[q] = xrow[lane + 64 * q];
            dot += xv[q].x * wv[q].x + xv[q].y * wv[q].y +
                   xv[q].z * wv[q].z + xv[q].w * wv[q].w;
        }
#pragma unroll
        for (int off = 32; off > 0; off >>= 1) dot += __shfl_xor(dot, off, 64);
        const float wrow = dot + bias;
        wacc += wrow;
#pragma unroll
        for (int q = 0; q < 8; ++q) {
            acc[4 * q + 0] += wrow * xv[q].x;
            acc[4 * q + 1] += wrow * xv[q].y;
            acc[4 * q + 2] += wrow * xv[q].z;
            acc[4 * q + 3] += wrow * xv[q].w;
            orow[lane + 64 * q] = xv[q];
        }
    }
#pragma unroll
    for (int q = 0; q < 8; ++q) {
        f32x4 s;
        s.x = acc[4 * q];     s.y = acc[4 * q + 1];
        s.z = acc[4 * q + 2]; s.w = acc[4 * q + 3];
        reinterpret_cast<f32x4*>(&lnum[wave][0])[lane + 64 * q] = s;
    }
    if (lane == 0) lw[wave] = wacc;
    __syncthreads();
    for (int c = tid; c < C; c += 256) {
        float s = lnum[0][c] + lnum[1][c] + lnum[2][c] + lnum[3][c];
        atomicAdd(&xnew[(size_t)(N + seg) * C + c], s);
    }
    if (tid == 0) atomicAdd(&wseg[seg], lw[0] + lw[1] + lw[2] + lw[3]);
}
__global__ __launch_bounds__(256) void k_div(float* __restrict__ xnew,
                                             const float* __restrict__ wseg) {
    int idx = blockIdx.x * 256 + threadIdx.x;
    if (idx < 4 * C) xnew[(size_t)N * C + idx] /= wseg[idx >> 11];
}
__global__ __launch_bounds__(256) void k_nz_only(float* __restrict__ adj) {
    const int t = blockIdx.x * 256 + threadIdx.x;
    if (t < N) {
        adj[(size_t)t * ND + t] = C_DIAG;
        adj[(size_t)t * ND + N + (t >> 11)] = C_LINK;
    } else if (t < N + 4 * 2052) {
        const int u = t - N;
        const int i = u / 2052;
        const int j = u - i * 2052;
        const size_t rowb = (size_t)(N + i) * ND;
        if (j < 2048) adj[rowb + i * 2048 + j] = C_LINK;
        else          adj[rowb + N + (j - 2048)] = C_BLK;
    }
}

// ---------------------------------------------------------------------------
extern "C" void kernel_launch(void* const* d_in, const int* in_sizes, int n_in,
                              void* d_out, int out_size, void* d_ws, size_t ws_size,
                              hipStream_t stream) {
    const float* x    = (const float*)d_in[0];
    const float* attw = (const float*)d_in[1];
    const float* attb = (const float*)d_in[2];
    float* xnew = (float*)d_out;                   // [8196, 2048]
    float* adj  = (float*)d_out + XNEW_ELEMS;      // [8196, 8196]

    const size_t ws_need = (PARTS + (size_t)PARTS * C) * sizeof(float); // ~8.4 MB
    if (ws_size >= ws_need) {
        float* wpart = (float*)d_ws;               // [1024]
        float* part  = (float*)d_ws + PARTS;       // [1024][C]
        k_att<<<ATT_BLOCKS, 256, 0, stream>>>(x, attw, attb, xnew, part, wpart);
        hipMemsetAsync(adj, 0, ADJ_ELEMS * sizeof(float), stream);
        // blocks 0-7: centers; blocks 8..72: nonzero scatter (16400 threads)
        k_centers_nz<<<8 + (N + 4 * 2052 + 255) / 256, 256, 0, stream>>>(
            part, wpart, xnew, adj);
    } else {                                        // atomic fallback
        float* wseg = (float*)d_ws;                // [4]
        k_zero<<<32, 256, 0, stream>>>(xnew, wseg);
        k_att_atomic<<<ATT_BLOCKS, 256, 0, stream>>>(x, attw, attb, xnew, wseg);
        k_div<<<32, 256, 0, stream>>>(xnew, wseg);
        hipMemsetAsync(adj, 0, ADJ_ELEMS * sizeof(float), stream);
        k_nz_only<<<(N + 4 * 2052 + 255) / 256, 256, 0, stream>>>(adj);
    }
}

// Round 8
// 102.925 us; speedup vs baseline: 1.2247x; 1.1488x over previous
//
#include <hip/hip_runtime.h>

// Problem constants
constexpr int N = 8192;
constexpr int C = 2048;
constexpr int ND = N + 4;                       // 8196
constexpr size_t XNEW_ELEMS = (size_t)ND * C;   // 16785408
constexpr size_t ADJ_ELEMS  = (size_t)ND * ND;  // 67174416
constexpr int ATT_BLOCKS = 1024;                // 8 rows per block, 2 per wave
constexpr int KB_PER_SEG = ATT_BLOCKS / 4;      // 256 partials per segment

#define C_DIAG 0.5f
#define C_LINK 0.015609764f                     /* 1/sqrt(2*2052) */
#define C_BLK  (1.0f / 2052.0f)

typedef float f32x4 __attribute__((ext_vector_type(4)));

// ---------------------------------------------------------------------------
// Scatter adj nonzeros (after the bulk memset-to-zero). ~16400 threads.
__global__ __launch_bounds__(256) void k_adj_nz(float* __restrict__ adj) {
    const int t = blockIdx.x * 256 + threadIdx.x;
    if (t < N) {
        adj[(size_t)t * ND + t] = C_DIAG;                 // diagonal
        adj[(size_t)t * ND + N + (t >> 11)] = C_LINK;     // row -> its center
    } else if (t < N + 4 * 2052) {
        const int u = t - N;
        const int i = u / 2052;                           // center index 0..3
        const int j = u - i * 2052;
        const size_t rowb = (size_t)(N + i) * ND;
        if (j < 2048) adj[rowb + i * 2048 + j] = C_LINK;  // center -> segment
        else          adj[rowb + N + (j - 2048)] = C_BLK; // 4x4 center block
    }
}

// ---------------------------------------------------------------------------
// Attention pass. R8: 1024 blocks (vs R2's 512) for 4 blocks/CU latency
// hiding; 8 rows/block, 2 rows per wave; LDS block-combine -> part[block][C].
template <bool USE_WS>
__global__ __launch_bounds__(256) void k_att(const float* __restrict__ x,
                                             const float* __restrict__ attw,
                                             const float* __restrict__ attb,
                                             float* __restrict__ xnew,
                                             float* __restrict__ part,
                                             float* __restrict__ wpart) {
    __shared__ float lnum[4][C];               // 32 KiB per-wave partials
    __shared__ float lw[4];

    const int tid  = threadIdx.x;
    const int wave = tid >> 6;
    const int lane = tid & 63;
    const int row0 = blockIdx.x * 8;
    const int seg  = blockIdx.x >> 8;          // 256 blocks per segment
    const float bias = attb[0];

    f32x4 wv[8];
#pragma unroll
    for (int q = 0; q < 8; ++q)
        wv[q] = reinterpret_cast<const f32x4*>(attw)[lane + 64 * q];

    float acc[32];
#pragma unroll
    for (int k = 0; k < 32; ++k) acc[k] = 0.0f;
    float wacc = 0.0f;

    for (int r = 0; r < 2; ++r) {
        const int row = row0 + wave * 2 + r;
        const f32x4* xrow = reinterpret_cast<const f32x4*>(x + (size_t)row * C);
        f32x4* orow = reinterpret_cast<f32x4*>(xnew + (size_t)row * C);

        f32x4 xv[8];
        float dot = 0.0f;
#pragma unroll
        for (int q = 0; q < 8; ++q) {
            xv[q] = xrow[lane + 64 * q];
            dot += xv[q].x * wv[q].x + xv[q].y * wv[q].y +
                   xv[q].z * wv[q].z + xv[q].w * wv[q].w;
        }
#pragma unroll
        for (int off = 32; off > 0; off >>= 1) dot += __shfl_xor(dot, off, 64);
        const float wrow = dot + bias;
        wacc += wrow;
#pragma unroll
        for (int q = 0; q < 8; ++q) {
            acc[4 * q + 0] += wrow * xv[q].x;
            acc[4 * q + 1] += wrow * xv[q].y;
            acc[4 * q + 2] += wrow * xv[q].z;
            acc[4 * q + 3] += wrow * xv[q].w;
            orow[lane + 64 * q] = xv[q];       // x_new head copy
        }
    }

#pragma unroll
    for (int q = 0; q < 8; ++q) {
        f32x4 s;
        s.x = acc[4 * q];     s.y = acc[4 * q + 1];
        s.z = acc[4 * q + 2]; s.w = acc[4 * q + 3];
        reinterpret_cast<f32x4*>(&lnum[wave][0])[lane + 64 * q] = s;
    }
    if (lane == 0) lw[wave] = wacc;            // wacc is wave-uniform
    __syncthreads();

    const f32x4* l0 = reinterpret_cast<const f32x4*>(&lnum[0][0]);
    const f32x4* l1 = reinterpret_cast<const f32x4*>(&lnum[1][0]);
    const f32x4* l2 = reinterpret_cast<const f32x4*>(&lnum[2][0]);
    const f32x4* l3 = reinterpret_cast<const f32x4*>(&lnum[3][0]);
#pragma unroll
    for (int c4 = tid; c4 < C / 4; c4 += 256) {
        f32x4 s = l0[c4] + l1[c4] + l2[c4] + l3[c4];
        if constexpr (USE_WS) {
            reinterpret_cast<f32x4*>(part + (size_t)blockIdx.x * C)[c4] = s;
        } else {
            float* dst = &xnew[(size_t)(N + seg) * C + 4 * c4];
            atomicAdd(dst + 0, s.x); atomicAdd(dst + 1, s.y);
            atomicAdd(dst + 2, s.z); atomicAdd(dst + 3, s.w);
        }
    }
    if (tid == 0) {
        const float wb = lw[0] + lw[1] + lw[2] + lw[3];
        if constexpr (USE_WS) wpart[blockIdx.x] = wb;
        else                  atomicAdd(&wpart[seg], wb);
    }
}

// ---------------------------------------------------------------------------
// centers[seg][c] = sum_k part[seg*256+k][c] / sum_k wpart[seg*256+k]
// 32 blocks x 256 = 8192 threads, one column each, 256-deep partial loop.
__global__ __launch_bounds__(256) void k_centers(const float* __restrict__ part,
                                                 const float* __restrict__ wpart,
                                                 float* __restrict__ xnew) {
    const int idx = blockIdx.x * 256 + threadIdx.x;   // 0..8191
    const int seg = idx >> 11;
    const int c   = idx & 2047;
    float wsum = 0.0f;
#pragma unroll 8
    for (int k = 0; k < KB_PER_SEG; ++k) wsum += wpart[seg * KB_PER_SEG + k];
    float s = 0.0f;
#pragma unroll 8
    for (int k = 0; k < KB_PER_SEG; ++k)
        s += part[(size_t)(seg * KB_PER_SEG + k) * C + c];
    xnew[(size_t)(N + seg) * C + c] = s / wsum;
}

// ---------------------------------------------------------------------------
// Fallback-path helpers (used only if ws is tiny): zero + divide.
__global__ __launch_bounds__(256) void k_zero(float* __restrict__ xnew,
                                              float* __restrict__ wseg) {
    int idx = blockIdx.x * 256 + threadIdx.x;
    if (idx < 4 * C) xnew[(size_t)N * C + idx] = 0.0f;
    if (idx < 4) wseg[idx] = 0.0f;
}
__global__ __launch_bounds__(256) void k_div(float* __restrict__ xnew,
                                             const float* __restrict__ wseg) {
    int idx = blockIdx.x * 256 + threadIdx.x;
    if (idx < 4 * C) xnew[(size_t)N * C + idx] /= wseg[idx >> 11];
}

// ---------------------------------------------------------------------------
extern "C" void kernel_launch(void* const* d_in, const int* in_sizes, int n_in,
                              void* d_out, int out_size, void* d_ws, size_t ws_size,
                              hipStream_t stream) {
    const float* x    = (const float*)d_in[0];
    const float* attw = (const float*)d_in[1];
    const float* attb = (const float*)d_in[2];
    float* xnew = (float*)d_out;                   // [8196, 2048]
    float* adj  = (float*)d_out + XNEW_ELEMS;      // [8196, 8196]

    // adj: bulk zero via fill path FIRST (R2's proven order), then scatter.
    hipMemsetAsync(adj, 0, ADJ_ELEMS * sizeof(float), stream);
    k_adj_nz<<<(N + 4 * 2052 + 255) / 256, 256, 0, stream>>>(adj);

    const size_t ws_need = (2048 + (size_t)ATT_BLOCKS * C) * sizeof(float); // ~8.4 MB
    if (ws_size >= ws_need) {
        float* wpart = (float*)d_ws;               // [1024]
        float* part  = (float*)d_ws + 2048;        // [1024][C]
        k_att<true><<<ATT_BLOCKS, 256, 0, stream>>>(x, attw, attb, xnew, part, wpart);
        k_centers<<<32, 256, 0, stream>>>(part, wpart, xnew);
    } else {                                        // atomic fallback
        float* wseg = (float*)d_ws;                // [4]
        k_zero<<<32, 256, 0, stream>>>(xnew, wseg);
        k_att<false><<<ATT_BLOCKS, 256, 0, stream>>>(x, attw, attb, xnew, nullptr, wseg);
        k_div<<<32, 256, 0, stream>>>(xnew, wseg);
    }
}

// Round 9
// 100.080 us; speedup vs baseline: 1.2596x; 1.0284x over previous
//
#include <hip/hip_runtime.h>

// Problem constants
constexpr int N = 8192;
constexpr int C = 2048;
constexpr int ND = N + 4;                       // 8196
constexpr size_t XNEW_ELEMS = (size_t)ND * C;   // 16785408

#define C_DIAG 0.5f
#define C_LINK 0.015609764f                     /* 1/sqrt(2*2052) */
#define C_BLK  (1.0f / 2052.0f)

typedef float f32x4 __attribute__((ext_vector_type(4)));

// ---------------------------------------------------------------------------
// adj writer, maximally fill-like: 2D grid, blockIdx.y = row (scalar/uniform),
// chunk = blockIdx.x*256+tid (no division anywhere). One 16B store per
// thread; row-dependent selectors are SGPR-resident; per-lane work is 2
// compares + cndmasks. Nonzeros folded in -> replaces memset + nz scatter.
// Row byte length 8196*4 = 32784 is 16B-divisible, so every row is aligned.
__global__ __launch_bounds__(256) void k_adj2d(float* __restrict__ adj) {
    const int row   = blockIdx.y;                        // 0..8195, uniform
    const int chunk = blockIdx.x * 256 + threadIdx.x;    // 0..2303
    if (chunk >= ND / 4) return;                         // 2049 chunks per row
    f32x4 v;
    if (row < N) {
        const int  dgc = row >> 2;                       // scalar
        const int  r3  = row & 3;                        // scalar
        const int  sg  = row >> 11;                      // scalar
        const bool dg  = (chunk == dgc);                 // vector cmp
        const bool lk  = (chunk == 2048);                // vector cmp
        v.x = (dg && r3 == 0) ? C_DIAG : ((lk && sg == 0) ? C_LINK : 0.0f);
        v.y = (dg && r3 == 1) ? C_DIAG : ((lk && sg == 1) ? C_LINK : 0.0f);
        v.z = (dg && r3 == 2) ? C_DIAG : ((lk && sg == 2) ? C_LINK : 0.0f);
        v.w = (dg && r3 == 3) ? C_DIAG : ((lk && sg == 3) ? C_LINK : 0.0f);
    } else {
        const int a = row - N;                           // scalar 0..3
        const float f = (chunk == 2048) ? C_BLK
                      : (((chunk >> 9) == a) ? C_LINK : 0.0f);
        v.x = f; v.y = f; v.z = f; v.w = f;
    }
    reinterpret_cast<f32x4*>(adj + (size_t)row * ND)[chunk] = v;
}

// ---------------------------------------------------------------------------
// Attention pass — R2's proven shape verbatim: 512 blocks, 16 rows/block,
// 4 rows/wave, LDS block-combine -> part[block][C] (+ wpart[block]).
template <bool USE_WS>
__global__ __launch_bounds__(256) void k_att(const float* __restrict__ x,
                                             const float* __restrict__ attw,
                                             const float* __restrict__ attb,
                                             float* __restrict__ xnew,
                                             float* __restrict__ part,
                                             float* __restrict__ wpart) {
    __shared__ float lnum[4][C];               // 32 KiB per-wave partials
    __shared__ float lw[4];

    const int tid  = threadIdx.x;
    const int wave = tid >> 6;
    const int lane = tid & 63;
    const int row0 = blockIdx.x * 16;
    const int seg  = blockIdx.x >> 7;          // 128 blocks per segment
    const float bias = attb[0];

    f32x4 wv[8];
#pragma unroll
    for (int q = 0; q < 8; ++q)
        wv[q] = reinterpret_cast<const f32x4*>(attw)[lane + 64 * q];

    float acc[32];
#pragma unroll
    for (int k = 0; k < 32; ++k) acc[k] = 0.0f;
    float wacc = 0.0f;

    for (int r = 0; r < 4; ++r) {
        const int row = row0 + wave * 4 + r;
        const f32x4* xrow = reinterpret_cast<const f32x4*>(x + (size_t)row * C);
        f32x4* orow = reinterpret_cast<f32x4*>(xnew + (size_t)row * C);

        f32x4 xv[8];
        float dot = 0.0f;
#pragma unroll
        for (int q = 0; q < 8; ++q) {
            xv[q] = xrow[lane + 64 * q];
            dot += xv[q].x * wv[q].x + xv[q].y * wv[q].y +
                   xv[q].z * wv[q].z + xv[q].w * wv[q].w;
        }
#pragma unroll
        for (int off = 32; off > 0; off >>= 1) dot += __shfl_xor(dot, off, 64);
        const float wrow = dot + bias;
        wacc += wrow;
#pragma unroll
        for (int q = 0; q < 8; ++q) {
            acc[4 * q + 0] += wrow * xv[q].x;
            acc[4 * q + 1] += wrow * xv[q].y;
            acc[4 * q + 2] += wrow * xv[q].z;
            acc[4 * q + 3] += wrow * xv[q].w;
            orow[lane + 64 * q] = xv[q];       // x_new head copy
        }
    }

#pragma unroll
    for (int q = 0; q < 8; ++q) {
        f32x4 s;
        s.x = acc[4 * q];     s.y = acc[4 * q + 1];
        s.z = acc[4 * q + 2]; s.w = acc[4 * q + 3];
        reinterpret_cast<f32x4*>(&lnum[wave][0])[lane + 64 * q] = s;
    }
    if (lane == 0) lw[wave] = wacc;            // wacc is wave-uniform
    __syncthreads();

    const f32x4* l0 = reinterpret_cast<const f32x4*>(&lnum[0][0]);
    const f32x4* l1 = reinterpret_cast<const f32x4*>(&lnum[1][0]);
    const f32x4* l2 = reinterpret_cast<const f32x4*>(&lnum[2][0]);
    const f32x4* l3 = reinterpret_cast<const f32x4*>(&lnum[3][0]);
#pragma unroll
    for (int c4 = tid; c4 < C / 4; c4 += 256) {
        f32x4 s = l0[c4] + l1[c4] + l2[c4] + l3[c4];
        if constexpr (USE_WS) {
            reinterpret_cast<f32x4*>(part + (size_t)blockIdx.x * C)[c4] = s;
        } else {
            float* dst = &xnew[(size_t)(N + seg) * C + 4 * c4];
            atomicAdd(dst + 0, s.x); atomicAdd(dst + 1, s.y);
            atomicAdd(dst + 2, s.z); atomicAdd(dst + 3, s.w);
        }
    }
    if (tid == 0) {
        const float wb = lw[0] + lw[1] + lw[2] + lw[3];
        if constexpr (USE_WS) wpart[blockIdx.x] = wb;
        else                  atomicAdd(&wpart[seg], wb);
    }
}

// ---------------------------------------------------------------------------
// centers[seg][c] = sum_k part[seg*128+k][c] / sum_k wpart[seg*128+k]
__global__ __launch_bounds__(256) void k_centers(const float* __restrict__ part,
                                                 const float* __restrict__ wpart,
                                                 float* __restrict__ xnew) {
    const int idx = blockIdx.x * 256 + threadIdx.x;   // 0..8191
    const int seg = idx >> 11;
    const int c   = idx & 2047;
    float wsum = 0.0f;
#pragma unroll 8
    for (int k = 0; k < 128; ++k) wsum += wpart[seg * 128 + k];
    float s = 0.0f;
#pragma unroll 8
    for (int k = 0; k < 128; ++k) s += part[(size_t)(seg * 128 + k) * C + c];
    xnew[(size_t)(N + seg) * C + c] = s / wsum;
}

// ---------------------------------------------------------------------------
// Fallback-path helpers (used only if ws is tiny): zero + divide.
__global__ __launch_bounds__(256) void k_zero(float* __restrict__ xnew,
                                              float* __restrict__ wseg) {
    int idx = blockIdx.x * 256 + threadIdx.x;
    if (idx < 4 * C) xnew[(size_t)N * C + idx] = 0.0f;
    if (idx < 4) wseg[idx] = 0.0f;
}
__global__ __launch_bounds__(256) void k_div(float* __restrict__ xnew,
                                             const float* __restrict__ wseg) {
    int idx = blockIdx.x * 256 + threadIdx.x;
    if (idx < 4 * C) xnew[(size_t)N * C + idx] /= wseg[idx >> 11];
}

// ---------------------------------------------------------------------------
extern "C" void kernel_launch(void* const* d_in, const int* in_sizes, int n_in,
                              void* d_out, int out_size, void* d_ws, size_t ws_size,
                              hipStream_t stream) {
    const float* x    = (const float*)d_in[0];
    const float* attw = (const float*)d_in[1];
    const float* attb = (const float*)d_in[2];
    float* xnew = (float*)d_out;                   // [8196, 2048]
    float* adj  = (float*)d_out + XNEW_ELEMS;      // [8196, 8196]

    // adj: trivial 2D pattern-store (replaces memset + nz scatter).
    // 9 x-blocks cover 2049 chunks/row; 8196 y-blocks = rows.
    k_adj2d<<<dim3(9, ND), 256, 0, stream>>>(adj);

    const size_t ws_need = (1024 + (size_t)512 * C) * sizeof(float);  // ~4.2 MB
    if (ws_size >= ws_need) {
        float* wpart = (float*)d_ws;               // [512]
        float* part  = (float*)d_ws + 1024;        // [512][C]
        k_att<true><<<N / 16, 256, 0, stream>>>(x, attw, attb, xnew, part, wpart);
        k_centers<<<32, 256, 0, stream>>>(part, wpart, xnew);
    } else {                                        // atomic fallback
        float* wseg = (float*)d_ws;                // [4]
        k_zero<<<32, 256, 0, stream>>>(xnew, wseg);
        k_att<false><<<N / 16, 256, 0, stream>>>(x, attw, attb, xnew, nullptr, wseg);
        k_div<<<32, 256, 0, stream>>>(xnew, wseg);
    }
}